// Round 2
// baseline (4708.845 us; speedup 1.0000x reference)
//
#include <hip/hip_runtime.h>
#include <math.h>

#define N 96
#define NN 9216        // N*N
#define LATENT 256
#define OUT_DIM 4656   // N*(N+1)/2
#define D1_IN 9472     // NN + LATENT
#define MPM_ITERS 50
#define MPM_BLOCKS 24
#define NRM_SLOTS 24

// workspace offsets (in floats)
#define OFF_PMU    0        // 128*256
#define OFF_PLS    32768    // 128*256
#define OFF_MU     65536    // 256
#define OFF_LS     65792    // 256
#define OFF_PD1    66048    // 128*256
#define OFF_Y      98816    // 256
#define OFF_KL     99072    // 1 (pad to 64)
#define OFF_PD2    99136    // 8*4656
#define OFF_OUT    136384   // 4656 (pad)
#define OFF_REC    141056   // 9216
#define OFF_B      150272   // 9216
#define OFF_D      159488   // 9216
#define OFF_CCNT   168704   // 96 ints
#define OFF_CCOL   168800   // 9216 ints
#define OFF_CVAL   178016   // 9216
#define OFF_XA     187232   // 9216
#define OFF_XB     196448   // 9216
#define OFF_NRM    205664   // 51*24

__device__ __forceinline__ int triu_idx(int i, int j) { // requires i<=j
    return i * N - (i * (i - 1)) / 2 + (j - i);
}

// ---- MLP stage 1: partial dot products for mu and logstd --------------------
__global__ __launch_bounds__(256) void k_muls_partial(
        const float* __restrict__ h, const float* __restrict__ Wmu,
        const float* __restrict__ Wls, float* __restrict__ pmu,
        float* __restrict__ pls) {
    int j = threadIdx.x;
    int c = blockIdx.x;      // 0..127, 72 rows each
    int k0 = c * 72;
    float amu = 0.f, als = 0.f;
    #pragma unroll 4
    for (int k = k0; k < k0 + 72; ++k) {
        float hv = h[k];
        amu = fmaf(hv, Wmu[k * LATENT + j], amu);
        als = fmaf(hv, Wls[k * LATENT + j], als);
    }
    pmu[c * LATENT + j] = amu;
    pls[c * LATENT + j] = als;
}

__global__ __launch_bounds__(128) void k_muls_reduce(
        const float* __restrict__ pmu, const float* __restrict__ pls,
        const float* __restrict__ bmu, const float* __restrict__ bls,
        float* __restrict__ mu, float* __restrict__ ls) {
    int g = blockIdx.x * 128 + threadIdx.x;   // 0..511
    int j = g & 255;
    const float* p = (g < 256) ? pmu : pls;
    float s = 0.f;
    for (int c = 0; c < 128; ++c) s += p[c * LATENT + j];
    if (g < 256) mu[j] = s + bmu[j];
    else         ls[j] = s + bls[j];
}

// ---- MLP stage 2: decoder layer 1 ------------------------------------------
__global__ __launch_bounds__(256) void k_d1_partial(
        const float* __restrict__ h, const float* __restrict__ mu,
        const float* __restrict__ Wd1, float* __restrict__ pd1) {
    int j = threadIdx.x;
    int c = blockIdx.x;   // 0..127, 74 rows each (9472 = 128*74)
    int k0 = c * 74;
    float acc = 0.f;
    for (int k = k0; k < k0 + 74; ++k) {
        float vv = (k < NN) ? h[k] : mu[k - NN];
        acc = fmaf(vv, Wd1[k * LATENT + j], acc);
    }
    pd1[c * LATENT + j] = acc;
}

__global__ __launch_bounds__(256) void k_d1_reduce_kl(
        const float* __restrict__ pd1, const float* __restrict__ bd1,
        const float* __restrict__ mu, const float* __restrict__ ls,
        float* __restrict__ y, float* __restrict__ klp) {
    int j = threadIdx.x;
    float s = 0.f;
    for (int c = 0; c < 128; ++c) s += pd1[c * LATENT + j];
    s += bd1[j];
    y[j] = fmaxf(s, 0.f);
    float m = mu[j], l = ls[j];
    float v = 1.f + l - m * m - expf(l);
    __shared__ float red[4];
    for (int off = 32; off; off >>= 1) v += __shfl_down(v, off);
    if ((threadIdx.x & 63) == 0) red[threadIdx.x >> 6] = v;
    __syncthreads();
    if (threadIdx.x == 0) {
        float t = red[0] + red[1] + red[2] + red[3];
        klp[0] = -0.5f * t / (float)NN;
    }
}

// ---- MLP stage 3: decoder layer 2 + sigmoid --------------------------------
__global__ __launch_bounds__(256) void k_d2_partial(
        const float* __restrict__ y, const float* __restrict__ Wd2,
        float* __restrict__ pd2) {
    int o = blockIdx.x * 256 + threadIdx.x;
    int g = blockIdx.y;   // 0..7, 32 k's each
    if (o >= OUT_DIM) return;
    float s = 0.f;
    int k0 = g * 32;
    #pragma unroll 8
    for (int k = k0; k < k0 + 32; ++k) s = fmaf(y[k], Wd2[k * OUT_DIM + o], s);
    pd2[g * OUT_DIM + o] = s;
}

__global__ __launch_bounds__(256) void k_out_final(
        const float* __restrict__ pd2, const float* __restrict__ bd2,
        float* __restrict__ outv) {
    int o = blockIdx.x * 256 + threadIdx.x;
    if (o >= OUT_DIM) return;
    float s = bd2[o];
    for (int g = 0; g < 8; ++g) s += pd2[g * OUT_DIM + o];
    outv[o] = 1.f / (1.f + expf(-s));
}

// ---- graph construction: rec, B, D, CSR(A), x0, nrm init -------------------
__global__ __launch_bounds__(256) void k_build(
        const float* __restrict__ adj, const float* __restrict__ outv,
        float* __restrict__ rec, float* __restrict__ Bm, float* __restrict__ Dm,
        int* __restrict__ ccnt, int* __restrict__ ccol, float* __restrict__ cval,
        float* __restrict__ xA, float* __restrict__ nrm) {
    int tid = threadIdx.x;
    __shared__ float d[N], nf[N], dr[N], nfr[N];
    for (int idx = tid; idx < NN; idx += 256) {
        int i = idx / N, j = idx - (idx / N) * N;
        int lo = (i < j) ? i : j, hi = (i < j) ? j : i;
        rec[idx] = outv[triu_idx(lo, hi)];
    }
    __syncthreads();
    if (tid < N) {
        int i = tid;
        d[i] = adj[i * N + i];
        dr[i] = rec[i * N + i];
        float s1 = 0.f, s2 = 0.f;
        for (int j = 0; j < N; ++j) { s1 += adj[i * N + j]; s2 += rec[i * N + j]; }
        nf[i] = s1; nfr[i] = s2;
    }
    __syncthreads();
    for (int idx = tid; idx < NN; idx += 256) {
        int i = idx / N, j = idx - (idx / N) * N;
        Bm[idx] = (i == j) ? 0.f : rec[idx] * dr[i] * dr[j];
        Dm[idx] = d[i] * dr[j] / (fabsf(nf[i] - nfr[j]) + 1.f);
        xA[idx] = 1.f / (float)N;
    }
    if (tid < N) {
        int i = tid, cnt = 0;
        for (int j = 0; j < N; ++j) {
            float av = adj[i * N + j] * d[i] * d[j];
            if (j != i && av != 0.f) { ccol[i * N + cnt] = j; cval[i * N + cnt] = av; ++cnt; }
        }
        ccnt[i] = cnt;
    }
    for (int idx = tid; idx < (MPM_ITERS + 1) * NRM_SLOTS; idx += 256) nrm[idx] = 0.f;
    if (tid == 0) nrm[0] = 1.f;   // ||x0||^2 = 9216 * (1/96)^2 = 1
}

// ---- one MPM iteration (a-column partition, deferred normalization) --------
__global__ __launch_bounds__(384) void k_mpm_iter(
        const float* __restrict__ xin, float* __restrict__ xout,
        const float* __restrict__ Bm, const float* __restrict__ Dm,
        const int* __restrict__ ccnt, const int* __restrict__ ccol,
        const float* __restrict__ cval,
        const float* __restrict__ nrm_in, float* __restrict__ nrm_out) {
    __shared__ float xs[N * 97];   // padded to kill bank conflicts
    __shared__ float Bs[N * 4];    // Bs[b*4+al] = B[a0+al][b]
    __shared__ float Ms[N * 4];
    __shared__ float red[8];
    int tid = threadIdx.x;
    int al = tid & 3, j = tid >> 2;
    int a0 = blockIdx.x * 4;
    for (int k = tid; k < NN; k += 384) {
        int r = k / N;
        xs[r * 97 + (k - r * N)] = xin[k];
    }
    {
        int b = tid >> 2;
        Bs[tid] = Bm[(a0 + al) * N + b];
    }
    float nsum = 0.f;
    for (int c = 0; c < NRM_SLOTS; ++c) nsum += nrm_in[c];
    float rn = rsqrtf(nsum);
    __syncthreads();
    // M[j, a0+al] = max_b x[j,b] * B[a0+al, b]
    float m = 0.f;
    const float* xr = &xs[j * 97];
    #pragma unroll 4
    for (int b = 0; b < N; ++b) m = fmaxf(m, xr[b] * Bs[b * 4 + al]);
    Ms[j * 4 + al] = m;
    __syncthreads();
    // xn[i,a] = x[i,a]*D[i,a] + sum_j A[i,j]*M[j,a], then scale by rn
    int i = j, a = a0 + al;
    float acc = xs[i * 97 + a] * Dm[i * N + a];
    int cn = ccnt[i];
    for (int c = 0; c < cn; ++c)
        acc = fmaf(cval[i * N + c], Ms[ccol[i * N + c] * 4 + al], acc);
    float o = acc * rn;
    xout[i * N + a] = o;
    float ps = o * o;
    for (int off = 32; off; off >>= 1) ps += __shfl_down(ps, off);
    if ((tid & 63) == 0) red[tid >> 6] = ps;
    __syncthreads();
    if (tid == 0) {
        float t = 0.f;
        for (int w = 0; w < 6; ++w) t += red[w];
        nrm_out[blockIdx.x] = t;
    }
}

// ---- Hungarian (f64, matches reference) + BCE + final output ---------------
__global__ __launch_bounds__(128) void k_hungarian_bce(
        const float* __restrict__ xfin, const float* __restrict__ nrm50,
        const float* __restrict__ adj, const float* __restrict__ outv,
        const float* __restrict__ klp, float* __restrict__ dout) {
    __shared__ float costs[NN];
    __shared__ double u[N + 1], v[N + 1], minv[N + 1];
    __shared__ int p[N + 1], way[N + 1], used[N + 1];
    __shared__ int indl[N];
    __shared__ double bc_delta;
    __shared__ int bc_i0, bc_j0, bc_j1, bc_done;
    __shared__ double rvv[2];
    __shared__ int rvj[2];
    __shared__ float redf[2];
    const double INF = 1e18;
    int tid = threadIdx.x;

    float nsum = 0.f;
    for (int c = 0; c < NRM_SLOTS; ++c) nsum += nrm50[c];
    float sc = rsqrtf(nsum);
    for (int k = tid; k < NN; k += 128) costs[k] = -(xfin[k] * sc);
    if (tid <= N) { u[tid] = 0.0; v[tid] = 0.0; p[tid] = 0; way[tid] = 0; }
    __syncthreads();

    for (int i = 1; i <= N; ++i) {
        if (tid <= N) { minv[tid] = INF; used[tid] = 0; }
        if (tid == 0) { p[0] = i; bc_j0 = 0; }
        __syncthreads();
        while (true) {
            if (tid == 0) { used[bc_j0] = 1; bc_i0 = p[bc_j0]; }
            __syncthreads();
            int i0 = bc_i0;
            int j0c = bc_j0;
            double myv = INF; int myj = 0;
            if (tid < N) {
                int jj = tid + 1;
                if (!used[jj]) {
                    double cur = (double)costs[(i0 - 1) * N + (jj - 1)] - u[i0] - v[jj];
                    if (cur < minv[jj]) { minv[jj] = cur; way[jj] = j0c; }
                    myv = minv[jj]; myj = jj;
                }
            }
            // argmin over 128 threads; strict < keeps the lowest j on ties
            for (int off = 32; off; off >>= 1) {
                double ov = __shfl_down(myv, off);
                int oj = __shfl_down(myj, off);
                if (ov < myv) { myv = ov; myj = oj; }
            }
            if ((tid & 63) == 0) { rvv[tid >> 6] = myv; rvj[tid >> 6] = myj; }
            __syncthreads();
            if (tid == 0) {
                double dv = rvv[0]; int dj = rvj[0];
                if (rvv[1] < dv) { dv = rvv[1]; dj = rvj[1]; }
                bc_delta = dv; bc_j1 = dj;
                bc_done = (p[dj] == 0);
                bc_j0 = dj;
            }
            __syncthreads();
            double delta = bc_delta;
            if (tid <= N) {
                if (used[tid]) { u[p[tid]] += delta; v[tid] -= delta; }
                else if (tid >= 1) minv[tid] -= delta;
            }
            __syncthreads();
            if (bc_done) break;
        }
        if (tid == 0) {   // augment along alternating path
            int j0 = bc_j1;
            while (j0) {
                int j1 = way[j0];
                p[j0] = p[j1];
                j0 = j1;
            }
        }
        __syncthreads();
    }
    // ind[c] = row matched to column c
    if (tid < N) indl[tid] = p[tid + 1] - 1;
    __syncthreads();
    // BCE over upper triangle of permuted adjacency
    float bsum = 0.f;
    for (int idx = tid; idx < NN; idx += 128) {
        int ii = idx / N, jj = idx - (idx / N) * N;
        if (jj >= ii) {
            float a = adj[indl[ii] * N + indl[jj]];
            float t = outv[triu_idx(ii, jj)];
            bsum += fmaxf(a, 0.f) - a * t + log1pf(expf(-fabsf(a)));
        }
    }
    for (int off = 32; off; off >>= 1) bsum += __shfl_down(bsum, off);
    if ((tid & 63) == 0) redf[tid >> 6] = bsum;
    __syncthreads();
    if (tid == 0) {
        float bce = (redf[0] + redf[1]) / (float)OUT_DIM;
        dout[0] = bce + klp[0];
    }
}

extern "C" void kernel_launch(void* const* d_in, const int* in_sizes, int n_in,
                              void* d_out, int out_size, void* d_ws, size_t ws_size,
                              hipStream_t stream) {
    const float* h   = (const float*)d_in[0];
    const float* adj = (const float*)d_in[1];
    const float* Wmu = (const float*)d_in[2];
    const float* bmu = (const float*)d_in[3];
    const float* Wls = (const float*)d_in[4];
    const float* bls = (const float*)d_in[5];
    const float* Wd1 = (const float*)d_in[6];
    const float* bd1 = (const float*)d_in[7];
    const float* Wd2 = (const float*)d_in[8];
    const float* bd2 = (const float*)d_in[9];

    float* ws   = (float*)d_ws;
    float* pmu  = ws + OFF_PMU;
    float* pls  = ws + OFF_PLS;
    float* mu   = ws + OFF_MU;
    float* ls   = ws + OFF_LS;
    float* pd1  = ws + OFF_PD1;
    float* y    = ws + OFF_Y;
    float* klp  = ws + OFF_KL;
    float* pd2  = ws + OFF_PD2;
    float* outv = ws + OFF_OUT;
    float* rec  = ws + OFF_REC;
    float* Bm   = ws + OFF_B;
    float* Dm   = ws + OFF_D;
    int*   ccnt = (int*)(ws + OFF_CCNT);
    int*   ccol = (int*)(ws + OFF_CCOL);
    float* cval = ws + OFF_CVAL;
    float* xA   = ws + OFF_XA;
    float* xB   = ws + OFF_XB;
    float* nrm  = ws + OFF_NRM;

    k_muls_partial<<<128, 256, 0, stream>>>(h, Wmu, Wls, pmu, pls);
    k_muls_reduce<<<4, 128, 0, stream>>>(pmu, pls, bmu, bls, mu, ls);
    k_d1_partial<<<128, 256, 0, stream>>>(h, mu, Wd1, pd1);
    k_d1_reduce_kl<<<1, 256, 0, stream>>>(pd1, bd1, mu, ls, y, klp);
    dim3 g5(19, 8);
    k_d2_partial<<<g5, 256, 0, stream>>>(y, Wd2, pd2);
    k_out_final<<<19, 256, 0, stream>>>(pd2, bd2, outv);
    k_build<<<1, 256, 0, stream>>>(adj, outv, rec, Bm, Dm, ccnt, ccol, cval, xA, nrm);
    for (int t = 0; t < MPM_ITERS; ++t) {
        const float* xi = (t & 1) ? xB : xA;
        float* xo = (t & 1) ? xA : xB;
        k_mpm_iter<<<MPM_BLOCKS, 384, 0, stream>>>(
            xi, xo, Bm, Dm, ccnt, ccol, cval,
            nrm + t * NRM_SLOTS, nrm + (t + 1) * NRM_SLOTS);
    }
    k_hungarian_bce<<<1, 128, 0, stream>>>(
        xA, nrm + MPM_ITERS * NRM_SLOTS, adj, outv, klp, (float*)d_out);
}

// Round 3
// 4159.601 us; speedup vs baseline: 1.1320x; 1.1320x over previous
//
#include <hip/hip_runtime.h>
#include <math.h>

#define N 96
#define NN 9216        // N*N
#define LATENT 256
#define OUT_DIM 4656   // N*(N+1)/2
#define D1_IN 9472     // NN + LATENT
#define MPM_ITERS 50
#define MPM_BLOCKS 24
#define NRM_SLOTS 24

// workspace offsets (in floats)
#define OFF_PMU    0        // 128*256
#define OFF_PLS    32768    // 128*256
#define OFF_MU     65536    // 256
#define OFF_LS     65792    // 256
#define OFF_PD1    66048    // 128*256
#define OFF_Y      98816    // 256
#define OFF_KL     99072    // 1 (pad to 64)
#define OFF_PD2    99136    // 8*4656
#define OFF_OUT    136384   // 4656 (pad)
#define OFF_REC    141056   // 9216
#define OFF_B      150272   // 9216
#define OFF_D      159488   // 9216
#define OFF_CCNT   168704   // 96 ints
#define OFF_CCOL   168800   // 9216 ints
#define OFF_CVAL   178016   // 9216
#define OFF_XA     187232   // 9216
#define OFF_XB     196448   // 9216
#define OFF_NRM    205664   // 51*24

__device__ __forceinline__ int triu_idx(int i, int j) { // requires i<=j
    return i * N - (i * (i - 1)) / 2 + (j - i);
}

// monotone map f64 -> sortable u64 (preserves total order of non-NaN doubles)
__device__ __forceinline__ unsigned long long dkey(double d) {
    unsigned long long b = (unsigned long long)__double_as_longlong(d);
    return (b >> 63) ? ~b : (b | 0x8000000000000000ull);
}
__device__ __forceinline__ double dunkey(unsigned long long k) {
    unsigned long long b = (k >> 63) ? (k & 0x7fffffffffffffffull) : ~k;
    return __longlong_as_double((long long)b);
}

// ---- MLP stage 1: partial dot products for mu and logstd --------------------
__global__ __launch_bounds__(256) void k_muls_partial(
        const float* __restrict__ h, const float* __restrict__ Wmu,
        const float* __restrict__ Wls, float* __restrict__ pmu,
        float* __restrict__ pls) {
    int j = threadIdx.x;
    int c = blockIdx.x;      // 0..127, 72 rows each
    int k0 = c * 72;
    float amu = 0.f, als = 0.f;
    #pragma unroll 4
    for (int k = k0; k < k0 + 72; ++k) {
        float hv = h[k];
        amu = fmaf(hv, Wmu[k * LATENT + j], amu);
        als = fmaf(hv, Wls[k * LATENT + j], als);
    }
    pmu[c * LATENT + j] = amu;
    pls[c * LATENT + j] = als;
}

__global__ __launch_bounds__(128) void k_muls_reduce(
        const float* __restrict__ pmu, const float* __restrict__ pls,
        const float* __restrict__ bmu, const float* __restrict__ bls,
        float* __restrict__ mu, float* __restrict__ ls) {
    int g = blockIdx.x * 128 + threadIdx.x;   // 0..511
    int j = g & 255;
    const float* p = (g < 256) ? pmu : pls;
    float s = 0.f;
    for (int c = 0; c < 128; ++c) s += p[c * LATENT + j];
    if (g < 256) mu[j] = s + bmu[j];
    else         ls[j] = s + bls[j];
}

// ---- MLP stage 2: decoder layer 1 ------------------------------------------
__global__ __launch_bounds__(256) void k_d1_partial(
        const float* __restrict__ h, const float* __restrict__ mu,
        const float* __restrict__ Wd1, float* __restrict__ pd1) {
    int j = threadIdx.x;
    int c = blockIdx.x;   // 0..127, 74 rows each (9472 = 128*74)
    int k0 = c * 74;
    float acc = 0.f;
    for (int k = k0; k < k0 + 74; ++k) {
        float vv = (k < NN) ? h[k] : mu[k - NN];
        acc = fmaf(vv, Wd1[k * LATENT + j], acc);
    }
    pd1[c * LATENT + j] = acc;
}

__global__ __launch_bounds__(256) void k_d1_reduce_kl(
        const float* __restrict__ pd1, const float* __restrict__ bd1,
        const float* __restrict__ mu, const float* __restrict__ ls,
        float* __restrict__ y, float* __restrict__ klp) {
    int j = threadIdx.x;
    float s = 0.f;
    for (int c = 0; c < 128; ++c) s += pd1[c * LATENT + j];
    s += bd1[j];
    y[j] = fmaxf(s, 0.f);
    float m = mu[j], l = ls[j];
    float v = 1.f + l - m * m - expf(l);
    __shared__ float red[4];
    for (int off = 32; off; off >>= 1) v += __shfl_down(v, off);
    if ((threadIdx.x & 63) == 0) red[threadIdx.x >> 6] = v;
    __syncthreads();
    if (threadIdx.x == 0) {
        float t = red[0] + red[1] + red[2] + red[3];
        klp[0] = -0.5f * t / (float)NN;
    }
}

// ---- MLP stage 3: decoder layer 2 + sigmoid --------------------------------
__global__ __launch_bounds__(256) void k_d2_partial(
        const float* __restrict__ y, const float* __restrict__ Wd2,
        float* __restrict__ pd2) {
    int o = blockIdx.x * 256 + threadIdx.x;
    int g = blockIdx.y;   // 0..7, 32 k's each
    if (o >= OUT_DIM) return;
    float s = 0.f;
    int k0 = g * 32;
    #pragma unroll 8
    for (int k = k0; k < k0 + 32; ++k) s = fmaf(y[k], Wd2[k * OUT_DIM + o], s);
    pd2[g * OUT_DIM + o] = s;
}

__global__ __launch_bounds__(256) void k_out_final(
        const float* __restrict__ pd2, const float* __restrict__ bd2,
        float* __restrict__ outv) {
    int o = blockIdx.x * 256 + threadIdx.x;
    if (o >= OUT_DIM) return;
    float s = bd2[o];
    for (int g = 0; g < 8; ++g) s += pd2[g * OUT_DIM + o];
    outv[o] = 1.f / (1.f + expf(-s));
}

// ---- graph construction: rec, B, D, CSR(A), x0, nrm init -------------------
__global__ __launch_bounds__(256) void k_build(
        const float* __restrict__ adj, const float* __restrict__ outv,
        float* __restrict__ rec, float* __restrict__ Bm, float* __restrict__ Dm,
        int* __restrict__ ccnt, int* __restrict__ ccol, float* __restrict__ cval,
        float* __restrict__ xA, float* __restrict__ nrm) {
    int tid = threadIdx.x;
    __shared__ float d[N], nf[N], dr[N], nfr[N];
    for (int idx = tid; idx < NN; idx += 256) {
        int i = idx / N, j = idx - (idx / N) * N;
        int lo = (i < j) ? i : j, hi = (i < j) ? j : i;
        rec[idx] = outv[triu_idx(lo, hi)];
    }
    __syncthreads();
    if (tid < N) {
        int i = tid;
        d[i] = adj[i * N + i];
        dr[i] = rec[i * N + i];
        float s1 = 0.f, s2 = 0.f;
        for (int j = 0; j < N; ++j) { s1 += adj[i * N + j]; s2 += rec[i * N + j]; }
        nf[i] = s1; nfr[i] = s2;
    }
    __syncthreads();
    for (int idx = tid; idx < NN; idx += 256) {
        int i = idx / N, j = idx - (idx / N) * N;
        Bm[idx] = (i == j) ? 0.f : rec[idx] * dr[i] * dr[j];
        Dm[idx] = d[i] * dr[j] / (fabsf(nf[i] - nfr[j]) + 1.f);
        xA[idx] = 1.f / (float)N;
    }
    if (tid < N) {
        int i = tid, cnt = 0;
        for (int j = 0; j < N; ++j) {
            float av = adj[i * N + j] * d[i] * d[j];
            if (j != i && av != 0.f) { ccol[i * N + cnt] = j; cval[i * N + cnt] = av; ++cnt; }
        }
        ccnt[i] = cnt;
    }
    for (int idx = tid; idx < (MPM_ITERS + 1) * NRM_SLOTS; idx += 256) nrm[idx] = 0.f;
    if (tid == 0) nrm[0] = 1.f;   // ||x0||^2 = 9216 * (1/96)^2 = 1
}

// ---- one MPM iteration (a-column partition, deferred normalization) --------
__global__ __launch_bounds__(384) void k_mpm_iter(
        const float* __restrict__ xin, float* __restrict__ xout,
        const float* __restrict__ Bm, const float* __restrict__ Dm,
        const int* __restrict__ ccnt, const int* __restrict__ ccol,
        const float* __restrict__ cval,
        const float* __restrict__ nrm_in, float* __restrict__ nrm_out) {
    __shared__ float xs[N * 97];   // padded to kill bank conflicts
    __shared__ float Bs[N * 4];    // Bs[b*4+al] = B[a0+al][b]
    __shared__ float Ms[N * 4];
    __shared__ float red[8];
    int tid = threadIdx.x;
    int al = tid & 3, j = tid >> 2;
    int a0 = blockIdx.x * 4;
    for (int k = tid; k < NN; k += 384) {
        int r = k / N;
        xs[r * 97 + (k - r * N)] = xin[k];
    }
    {
        int b = tid >> 2;
        Bs[tid] = Bm[(a0 + al) * N + b];
    }
    float nsum = 0.f;
    for (int c = 0; c < NRM_SLOTS; ++c) nsum += nrm_in[c];
    float rn = rsqrtf(nsum);
    __syncthreads();
    // M[j, a0+al] = max_b x[j,b] * B[a0+al, b]
    float m = 0.f;
    const float* xr = &xs[j * 97];
    #pragma unroll 4
    for (int b = 0; b < N; ++b) m = fmaxf(m, xr[b] * Bs[b * 4 + al]);
    Ms[j * 4 + al] = m;
    __syncthreads();
    // xn[i,a] = x[i,a]*D[i,a] + sum_j A[i,j]*M[j,a], then scale by rn
    int i = j, a = a0 + al;
    float acc = xs[i * 97 + a] * Dm[i * N + a];
    int cn = ccnt[i];
    for (int c = 0; c < cn; ++c)
        acc = fmaf(cval[i * N + c], Ms[ccol[i * N + c] * 4 + al], acc);
    float o = acc * rn;
    xout[i * N + a] = o;
    float ps = o * o;
    for (int off = 32; off; off >>= 1) ps += __shfl_down(ps, off);
    if ((tid & 63) == 0) red[tid >> 6] = ps;
    __syncthreads();
    if (tid == 0) {
        float t = 0.f;
        for (int w = 0; w < 6; ++w) t += red[w];
        nrm_out[blockIdx.x] = t;
    }
}

// ---- Hungarian: single-wave, register-resident (f64 exact) + BCE -----------
// Lane l owns columns: slot0 = col l (0..63), slot1 = col 64+l (l<33 -> 64..96).
// Per-column state (v, minv, way, p, used) in registers; u[] and costs in LDS.
__global__ __launch_bounds__(64) void k_hungarian_bce(
        const float* __restrict__ xfin, const float* __restrict__ nrm50,
        const float* __restrict__ adj, const float* __restrict__ outv,
        const float* __restrict__ klp, float* __restrict__ dout) {
    __shared__ float costs[NN];
    __shared__ double u_sh[N + 1];
    __shared__ int indl[N];
    const double INF = 1e18;
    int l = threadIdx.x;   // 0..63
    bool has1 = (l < 33);

    float nsum = 0.f;
    for (int c = 0; c < NRM_SLOTS; ++c) nsum += nrm50[c];
    float sc = rsqrtf(nsum);
    for (int k = l; k < NN; k += 64) costs[k] = -(xfin[k] * sc);
    u_sh[l] = 0.0;
    if (has1) u_sh[64 + l] = 0.0;
    __syncthreads();

    // per-lane column state
    double v0 = 0.0, v1 = 0.0, minv0 = INF, minv1 = INF;
    int way0 = 0, way1 = 0, p0 = 0, p1 = 0;
    int used0 = 0, used1 = 0;
    const unsigned long long KINF = dkey(INF);

    for (int i = 1; i <= N; ++i) {
        minv0 = INF; minv1 = INF; used0 = 0; used1 = 0;
        if (l == 0) p0 = i;        // p[0] = i
        int j0 = 0;
        while (true) {
            // i0 = p[j0]; mark used[j0]
            int pv0 = __shfl(p0, j0 & 63);
            int pv1 = __shfl(p1, (j0 >= 64) ? (j0 - 64) : 0);
            int i0 = (j0 < 64) ? pv0 : pv1;
            if (j0 < 64) { if (l == j0) used0 = 1; }
            else         { if (l == j0 - 64) used1 = 1; }
            double u_i0 = u_sh[i0];          // ordered vs prev scatter by barrier below
            // candidate updates: cur = cost[i0-1][j-1] - u[i0] - v[j]
            if (l >= 1 && !used0) {
                double cur = (double)costs[(i0 - 1) * N + (l - 1)] - u_i0 - v0;
                if (cur < minv0) { minv0 = cur; way0 = j0; }
            }
            if (has1 && !used1) {
                double cur = (double)costs[(i0 - 1) * N + (63 + l)] - u_i0 - v1;
                if (cur < minv1) { minv1 = cur; way1 = j0; }
            }
            // argmin over free cols: key-only butterfly, then ballot for index
            unsigned long long ck0 = (l >= 1 && !used0) ? dkey(minv0 + 0.0) : KINF;
            unsigned long long ck1 = (has1 && !used1) ? dkey(minv1 + 0.0) : KINF;
            unsigned long long bv = (ck1 < ck0) ? ck1 : ck0;
            #pragma unroll
            for (int m = 32; m; m >>= 1) {
                unsigned long long ov = __shfl_xor(bv, m);
                if (ov < bv) bv = ov;
            }
            unsigned long long m0 = __ballot(ck0 == bv);
            unsigned long long m1 = __ballot(ck1 == bv);
            int j1 = m0 ? (__ffsll(m0) - 1) : (64 + __ffsll(m1) - 1);
            double delta = dunkey(bv);
            // updates: u[p[used]] += delta; v[used] -= delta; minv[free] -= delta
            if (used0) { u_sh[p0] += delta; v0 -= delta; }
            else if (l >= 1) minv0 -= delta;
            if (has1) {
                if (used1) { u_sh[p1] += delta; v1 -= delta; }
                else minv1 -= delta;
            }
            __syncthreads();   // order u scatter vs next-step broadcast read
            int q0 = __shfl(p0, j1 & 63);
            int q1 = __shfl(p1, (j1 >= 64) ? (j1 - 64) : 0);
            int pj1 = (j1 < 64) ? q0 : q1;
            j0 = j1;
            if (pj1 == 0) break;
        }
        // augment along alternating path (uniform control, shuffled reads)
        while (j0) {
            int w0 = __shfl(way0, j0 & 63);
            int w1 = __shfl(way1, (j0 >= 64) ? (j0 - 64) : 0);
            int w = (j0 < 64) ? w0 : w1;
            int q0 = __shfl(p0, w & 63);
            int q1 = __shfl(p1, (w >= 64) ? (w - 64) : 0);
            int pw = (w < 64) ? q0 : q1;
            if (j0 < 64) { if (l == j0) p0 = pw; }
            else         { if (l == j0 - 64) p1 = pw; }
            j0 = w;
        }
    }
    // ind[c] = row matched to column c+1, minus 1
    if (l >= 1) indl[l - 1] = p0 - 1;       // cols 1..63 -> ind[0..62]
    if (has1)   indl[63 + l] = p1 - 1;      // cols 64..96 -> ind[63..95]
    __syncthreads();
    // BCE over upper triangle of permuted adjacency
    float bsum = 0.f;
    for (int idx = l; idx < NN; idx += 64) {
        int ii = idx / N, jj = idx - (idx / N) * N;
        if (jj >= ii) {
            float a = adj[indl[ii] * N + indl[jj]];
            float t = outv[triu_idx(ii, jj)];
            bsum += fmaxf(a, 0.f) - a * t + log1pf(expf(-fabsf(a)));
        }
    }
    for (int off = 32; off; off >>= 1) bsum += __shfl_down(bsum, off);
    if (l == 0) {
        float bce = bsum / (float)OUT_DIM;
        dout[0] = bce + klp[0];
    }
}

extern "C" void kernel_launch(void* const* d_in, const int* in_sizes, int n_in,
                              void* d_out, int out_size, void* d_ws, size_t ws_size,
                              hipStream_t stream) {
    const float* h   = (const float*)d_in[0];
    const float* adj = (const float*)d_in[1];
    const float* Wmu = (const float*)d_in[2];
    const float* bmu = (const float*)d_in[3];
    const float* Wls = (const float*)d_in[4];
    const float* bls = (const float*)d_in[5];
    const float* Wd1 = (const float*)d_in[6];
    const float* bd1 = (const float*)d_in[7];
    const float* Wd2 = (const float*)d_in[8];
    const float* bd2 = (const float*)d_in[9];

    float* ws   = (float*)d_ws;
    float* pmu  = ws + OFF_PMU;
    float* pls  = ws + OFF_PLS;
    float* mu   = ws + OFF_MU;
    float* ls   = ws + OFF_LS;
    float* pd1  = ws + OFF_PD1;
    float* y    = ws + OFF_Y;
    float* klp  = ws + OFF_KL;
    float* pd2  = ws + OFF_PD2;
    float* outv = ws + OFF_OUT;
    float* rec  = ws + OFF_REC;
    float* Bm   = ws + OFF_B;
    float* Dm   = ws + OFF_D;
    int*   ccnt = (int*)(ws + OFF_CCNT);
    int*   ccol = (int*)(ws + OFF_CCOL);
    float* cval = ws + OFF_CVAL;
    float* xA   = ws + OFF_XA;
    float* xB   = ws + OFF_XB;
    float* nrm  = ws + OFF_NRM;

    k_muls_partial<<<128, 256, 0, stream>>>(h, Wmu, Wls, pmu, pls);
    k_muls_reduce<<<4, 128, 0, stream>>>(pmu, pls, bmu, bls, mu, ls);
    k_d1_partial<<<128, 256, 0, stream>>>(h, mu, Wd1, pd1);
    k_d1_reduce_kl<<<1, 256, 0, stream>>>(pd1, bd1, mu, ls, y, klp);
    dim3 g5(19, 8);
    k_d2_partial<<<g5, 256, 0, stream>>>(y, Wd2, pd2);
    k_out_final<<<19, 256, 0, stream>>>(pd2, bd2, outv);
    k_build<<<1, 256, 0, stream>>>(adj, outv, rec, Bm, Dm, ccnt, ccol, cval, xA, nrm);
    for (int t = 0; t < MPM_ITERS; ++t) {
        const float* xi = (t & 1) ? xB : xA;
        float* xo = (t & 1) ? xA : xB;
        k_mpm_iter<<<MPM_BLOCKS, 384, 0, stream>>>(
            xi, xo, Bm, Dm, ccnt, ccol, cval,
            nrm + t * NRM_SLOTS, nrm + (t + 1) * NRM_SLOTS);
    }
    k_hungarian_bce<<<1, 64, 0, stream>>>(
        xA, nrm + MPM_ITERS * NRM_SLOTS, adj, outv, klp, (float*)d_out);
}

// Round 4
// 2892.391 us; speedup vs baseline: 1.6280x; 1.4381x over previous
//
#include <hip/hip_runtime.h>
#include <math.h>

#define N 96
#define NN 9216        // N*N
#define LATENT 256
#define OUT_DIM 4656   // N*(N+1)/2
#define D1_IN 9472     // NN + LATENT
#define MPM_ITERS 50
#define MPM_BLOCKS 24
#define NRM_SLOTS 24

// workspace offsets (in floats)
#define OFF_PMU    0        // 128*256
#define OFF_PLS    32768    // 128*256
#define OFF_MU     65536    // 256
#define OFF_LS     65792    // 256
#define OFF_PD1    66048    // 128*256
#define OFF_Y      98816    // 256
#define OFF_KL     99072    // 1 (pad to 64)
#define OFF_PD2    99136    // 8*4656
#define OFF_OUT    136384   // 4656 (pad)
#define OFF_REC    141056   // 9216
#define OFF_B      150272   // 9216
#define OFF_D      159488   // 9216
#define OFF_CCNT   168704   // 96 ints
#define OFF_CCOL   168800   // 9216 ints
#define OFF_CVAL   178016   // 9216
#define OFF_XA     187232   // 9216
#define OFF_XB     196448   // 9216
#define OFF_NRM    205664   // 51*24

__device__ __forceinline__ int triu_idx(int i, int j) { // requires i<=j
    return i * N - (i * (i - 1)) / 2 + (j - i);
}

// monotone map f64 -> sortable u64 (preserves total order of non-NaN doubles)
__device__ __forceinline__ unsigned long long dkey(double d) {
    unsigned long long b = (unsigned long long)__double_as_longlong(d);
    return (b >> 63) ? ~b : (b | 0x8000000000000000ull);
}
__device__ __forceinline__ double dunkey(unsigned long long k) {
    unsigned long long b = (k >> 63) ? (k & 0x7fffffffffffffffull) : ~k;
    return __longlong_as_double((long long)b);
}

// wave64 min-reduce of u32 via DPP (VALU-only, no DS ops); result uniform.
// Pattern: row_shr 1/2/4/8 then row_bcast15/31 -> lane 63 holds full min.
__device__ __forceinline__ unsigned wave_min_u32(unsigned x) {
    const int id = (int)0xFFFFFFFF;   // identity for min (kept in invalid lanes)
    unsigned t;
    t = (unsigned)__builtin_amdgcn_update_dpp(id, (int)x, 0x111, 0xF, 0xF, false); if (t < x) x = t;
    t = (unsigned)__builtin_amdgcn_update_dpp(id, (int)x, 0x112, 0xF, 0xF, false); if (t < x) x = t;
    t = (unsigned)__builtin_amdgcn_update_dpp(id, (int)x, 0x114, 0xF, 0xF, false); if (t < x) x = t;
    t = (unsigned)__builtin_amdgcn_update_dpp(id, (int)x, 0x118, 0xF, 0xF, false); if (t < x) x = t;
    t = (unsigned)__builtin_amdgcn_update_dpp(id, (int)x, 0x142, 0xF, 0xF, false); if (t < x) x = t;
    t = (unsigned)__builtin_amdgcn_update_dpp(id, (int)x, 0x143, 0xF, 0xF, false); if (t < x) x = t;
    return (unsigned)__builtin_amdgcn_readlane((int)x, 63);
}

// ---- MLP stage 1: partial dot products for mu and logstd --------------------
__global__ __launch_bounds__(256) void k_muls_partial(
        const float* __restrict__ h, const float* __restrict__ Wmu,
        const float* __restrict__ Wls, float* __restrict__ pmu,
        float* __restrict__ pls) {
    int j = threadIdx.x;
    int c = blockIdx.x;      // 0..127, 72 rows each
    int k0 = c * 72;
    float amu = 0.f, als = 0.f;
    #pragma unroll 4
    for (int k = k0; k < k0 + 72; ++k) {
        float hv = h[k];
        amu = fmaf(hv, Wmu[k * LATENT + j], amu);
        als = fmaf(hv, Wls[k * LATENT + j], als);
    }
    pmu[c * LATENT + j] = amu;
    pls[c * LATENT + j] = als;
}

__global__ __launch_bounds__(128) void k_muls_reduce(
        const float* __restrict__ pmu, const float* __restrict__ pls,
        const float* __restrict__ bmu, const float* __restrict__ bls,
        float* __restrict__ mu, float* __restrict__ ls) {
    int g = blockIdx.x * 128 + threadIdx.x;   // 0..511
    int j = g & 255;
    const float* p = (g < 256) ? pmu : pls;
    float s = 0.f;
    for (int c = 0; c < 128; ++c) s += p[c * LATENT + j];
    if (g < 256) mu[j] = s + bmu[j];
    else         ls[j] = s + bls[j];
}

// ---- MLP stage 2: decoder layer 1 ------------------------------------------
__global__ __launch_bounds__(256) void k_d1_partial(
        const float* __restrict__ h, const float* __restrict__ mu,
        const float* __restrict__ Wd1, float* __restrict__ pd1) {
    int j = threadIdx.x;
    int c = blockIdx.x;   // 0..127, 74 rows each (9472 = 128*74)
    int k0 = c * 74;
    float acc = 0.f;
    for (int k = k0; k < k0 + 74; ++k) {
        float vv = (k < NN) ? h[k] : mu[k - NN];
        acc = fmaf(vv, Wd1[k * LATENT + j], acc);
    }
    pd1[c * LATENT + j] = acc;
}

__global__ __launch_bounds__(256) void k_d1_reduce_kl(
        const float* __restrict__ pd1, const float* __restrict__ bd1,
        const float* __restrict__ mu, const float* __restrict__ ls,
        float* __restrict__ y, float* __restrict__ klp) {
    int j = threadIdx.x;
    float s = 0.f;
    for (int c = 0; c < 128; ++c) s += pd1[c * LATENT + j];
    s += bd1[j];
    y[j] = fmaxf(s, 0.f);
    float m = mu[j], l = ls[j];
    float v = 1.f + l - m * m - expf(l);
    __shared__ float red[4];
    for (int off = 32; off; off >>= 1) v += __shfl_down(v, off);
    if ((threadIdx.x & 63) == 0) red[threadIdx.x >> 6] = v;
    __syncthreads();
    if (threadIdx.x == 0) {
        float t = red[0] + red[1] + red[2] + red[3];
        klp[0] = -0.5f * t / (float)NN;
    }
}

// ---- MLP stage 3: decoder layer 2 + sigmoid --------------------------------
__global__ __launch_bounds__(256) void k_d2_partial(
        const float* __restrict__ y, const float* __restrict__ Wd2,
        float* __restrict__ pd2) {
    int o = blockIdx.x * 256 + threadIdx.x;
    int g = blockIdx.y;   // 0..7, 32 k's each
    if (o >= OUT_DIM) return;
    float s = 0.f;
    int k0 = g * 32;
    #pragma unroll 8
    for (int k = k0; k < k0 + 32; ++k) s = fmaf(y[k], Wd2[k * OUT_DIM + o], s);
    pd2[g * OUT_DIM + o] = s;
}

__global__ __launch_bounds__(256) void k_out_final(
        const float* __restrict__ pd2, const float* __restrict__ bd2,
        float* __restrict__ outv) {
    int o = blockIdx.x * 256 + threadIdx.x;
    if (o >= OUT_DIM) return;
    float s = bd2[o];
    for (int g = 0; g < 8; ++g) s += pd2[g * OUT_DIM + o];
    outv[o] = 1.f / (1.f + expf(-s));
}

// ---- graph construction: rec, B, D, CSR(A), x0, nrm init -------------------
__global__ __launch_bounds__(256) void k_build(
        const float* __restrict__ adj, const float* __restrict__ outv,
        float* __restrict__ rec, float* __restrict__ Bm, float* __restrict__ Dm,
        int* __restrict__ ccnt, int* __restrict__ ccol, float* __restrict__ cval,
        float* __restrict__ xA, float* __restrict__ nrm) {
    int tid = threadIdx.x;
    __shared__ float d[N], nf[N], dr[N], nfr[N];
    for (int idx = tid; idx < NN; idx += 256) {
        int i = idx / N, j = idx - (idx / N) * N;
        int lo = (i < j) ? i : j, hi = (i < j) ? j : i;
        rec[idx] = outv[triu_idx(lo, hi)];
    }
    __syncthreads();
    if (tid < N) {
        int i = tid;
        d[i] = adj[i * N + i];
        dr[i] = rec[i * N + i];
        float s1 = 0.f, s2 = 0.f;
        for (int j = 0; j < N; ++j) { s1 += adj[i * N + j]; s2 += rec[i * N + j]; }
        nf[i] = s1; nfr[i] = s2;
    }
    __syncthreads();
    for (int idx = tid; idx < NN; idx += 256) {
        int i = idx / N, j = idx - (idx / N) * N;
        Bm[idx] = (i == j) ? 0.f : rec[idx] * dr[i] * dr[j];
        Dm[idx] = d[i] * dr[j] / (fabsf(nf[i] - nfr[j]) + 1.f);
        xA[idx] = 1.f / (float)N;
    }
    if (tid < N) {
        int i = tid, cnt = 0;
        for (int j = 0; j < N; ++j) {
            float av = adj[i * N + j] * d[i] * d[j];
            if (j != i && av != 0.f) { ccol[i * N + cnt] = j; cval[i * N + cnt] = av; ++cnt; }
        }
        ccnt[i] = cnt;
    }
    for (int idx = tid; idx < (MPM_ITERS + 1) * NRM_SLOTS; idx += 256) nrm[idx] = 0.f;
    if (tid == 0) nrm[0] = 1.f;   // ||x0||^2 = 9216 * (1/96)^2 = 1
}

// ---- one MPM iteration (a-column partition, deferred normalization) --------
__global__ __launch_bounds__(384) void k_mpm_iter(
        const float* __restrict__ xin, float* __restrict__ xout,
        const float* __restrict__ Bm, const float* __restrict__ Dm,
        const int* __restrict__ ccnt, const int* __restrict__ ccol,
        const float* __restrict__ cval,
        const float* __restrict__ nrm_in, float* __restrict__ nrm_out) {
    __shared__ float xs[N * 97];   // padded to kill bank conflicts
    __shared__ float Bs[N * 4];    // Bs[b*4+al] = B[a0+al][b]
    __shared__ float Ms[N * 4];
    __shared__ float red[8];
    int tid = threadIdx.x;
    int al = tid & 3, j = tid >> 2;
    int a0 = blockIdx.x * 4;
    for (int k = tid; k < NN; k += 384) {
        int r = k / N;
        xs[r * 97 + (k - r * N)] = xin[k];
    }
    {
        int b = tid >> 2;
        Bs[tid] = Bm[(a0 + al) * N + b];
    }
    float nsum = 0.f;
    for (int c = 0; c < NRM_SLOTS; ++c) nsum += nrm_in[c];
    float rn = rsqrtf(nsum);
    __syncthreads();
    // M[j, a0+al] = max_b x[j,b] * B[a0+al, b]
    float m = 0.f;
    const float* xr = &xs[j * 97];
    #pragma unroll 4
    for (int b = 0; b < N; ++b) m = fmaxf(m, xr[b] * Bs[b * 4 + al]);
    Ms[j * 4 + al] = m;
    __syncthreads();
    // xn[i,a] = x[i,a]*D[i,a] + sum_j A[i,j]*M[j,a], then scale by rn
    int i = j, a = a0 + al;
    float acc = xs[i * 97 + a] * Dm[i * N + a];
    int cn = ccnt[i];
    for (int c = 0; c < cn; ++c)
        acc = fmaf(cval[i * N + c], Ms[ccol[i * N + c] * 4 + al], acc);
    float o = acc * rn;
    xout[i * N + a] = o;
    float ps = o * o;
    for (int off = 32; off; off >>= 1) ps += __shfl_down(ps, off);
    if ((tid & 63) == 0) red[tid >> 6] = ps;
    __syncthreads();
    if (tid == 0) {
        float t = 0.f;
        for (int w = 0; w < 6; ++w) t += red[w];
        nrm_out[blockIdx.x] = t;
    }
}

// ---- Hungarian: single-wave, DPP argmin, readlane broadcasts, deferred u ---
// Lane l owns columns: slot0 = col l (0..63), slot1 = col 64+l (l<33 -> 64..96).
// v, minv, way, p, used, ud in registers; u[] (rows) and costs in LDS.
// Per-step DS traffic: 2 cost reads + 1 uniform u read (all overlap); argmin
// is DPP (VALU) + ballot; broadcasts are v_readlane (uniform index).
__global__ __launch_bounds__(64) void k_hungarian_bce(
        const float* __restrict__ xfin, const float* __restrict__ nrm50,
        const float* __restrict__ adj, const float* __restrict__ outv,
        const float* __restrict__ klp, float* __restrict__ dout) {
    __shared__ float costs[NN];
    __shared__ double u_sh[N + 1];
    __shared__ int indl[N];
    const double INF = 1e18;
    int l = threadIdx.x;   // 0..63
    bool has1 = (l < 33);

    float nsum = 0.f;
    for (int c = 0; c < NRM_SLOTS; ++c) nsum += nrm50[c];
    float sc = rsqrtf(nsum);
    for (int k = l; k < NN; k += 64) costs[k] = -(xfin[k] * sc);
    u_sh[l] = 0.0;
    if (has1) u_sh[64 + l] = 0.0;
    if (l == 0) u_sh[N] = 0.0;
    __syncthreads();

    // per-lane column state
    double v0 = 0.0, v1 = 0.0, minv0 = INF, minv1 = INF;
    int way0 = 0, way1 = 0, p0 = 0, p1 = 0;
    int used0 = 0, used1 = 0;
    const unsigned long long KINF = dkey(INF);

    for (int i = 1; i <= N; ++i) {
        minv0 = INF; minv1 = INF; used0 = 0; used1 = 0;
        double ud0 = 0.0, ud1 = 0.0;   // deferred u[p[col]] increments
        if (l == 0) p0 = i;            // p[0] = i
        int j0 = 0;
        int i0 = i;                    // = p[j0]; carried forward each step
        while (true) {
            // mark used[j0]
            if (j0 < 64) { if (l == j0) used0 = 1; }
            else         { if (l == j0 - 64) used1 = 1; }
            // u[i0] read: value is scan-start-stable (updates deferred)
            double u_i0 = u_sh[i0];
            int rowbase = (i0 - 1) * N;
            if (l >= 1 && !used0) {
                double cur = (double)costs[rowbase + (l - 1)] - u_i0 - v0;
                if (cur < minv0) { minv0 = cur; way0 = j0; }
            }
            if (has1 && !used1) {
                double cur = (double)costs[rowbase + 63 + l] - u_i0 - v1;
                if (cur < minv1) { minv1 = cur; way1 = j0; }
            }
            // lexicographic u64 argmin via two 32-bit DPP min phases
            unsigned long long ck0 = (l >= 1 && !used0) ? dkey(minv0 + 0.0) : KINF;
            unsigned long long ck1 = (has1 && !used1) ? dkey(minv1 + 0.0) : KINF;
            unsigned long long bv = (ck1 < ck0) ? ck1 : ck0;
            unsigned hi = (unsigned)(bv >> 32), lo = (unsigned)bv;
            unsigned minhi = wave_min_u32(hi);
            unsigned lom = (hi == minhi) ? lo : 0xFFFFFFFFu;
            unsigned minlo = wave_min_u32(lom);
            unsigned long long kmin = ((unsigned long long)minhi << 32) | minlo;
            unsigned long long m0 = __ballot(ck0 == kmin);
            unsigned long long m1 = __ballot(ck1 == kmin);
            int j1 = m0 ? (__ffsll(m0) - 1) : (64 + __ffsll(m1) - 1);
            double delta = dunkey(kmin);
            // updates: (deferred) u[p[used]] += delta; v[used] -= delta; minv[free] -= delta
            if (used0) { ud0 += delta; v0 -= delta; }
            else if (l >= 1) minv0 -= delta;
            if (has1) {
                if (used1) { ud1 += delta; v1 -= delta; }
                else minv1 -= delta;
            }
            int pj1 = (j1 < 64) ? __builtin_amdgcn_readlane(p0, j1)
                                : __builtin_amdgcn_readlane(p1, j1 - 64);
            j0 = j1; i0 = pj1;
            if (pj1 == 0) break;
        }
        // apply deferred u updates (pre-augmentation p; distinct rows -> no race)
        if (used0) u_sh[p0] += ud0;
        if (has1 && used1) u_sh[p1] += ud1;
        __syncthreads();   // order scatter vs next scan's u reads
        // augment along alternating path (uniform indices -> readlane)
        while (j0) {
            int w = (j0 < 64) ? __builtin_amdgcn_readlane(way0, j0)
                              : __builtin_amdgcn_readlane(way1, j0 - 64);
            int pw = (w < 64) ? __builtin_amdgcn_readlane(p0, w)
                              : __builtin_amdgcn_readlane(p1, w - 64);
            if (j0 < 64) { if (l == j0) p0 = pw; }
            else         { if (l == j0 - 64) p1 = pw; }
            j0 = w;
        }
    }
    // ind[c] = row matched to column c+1, minus 1
    if (l >= 1) indl[l - 1] = p0 - 1;       // cols 1..63 -> ind[0..62]
    if (has1)   indl[63 + l] = p1 - 1;      // cols 64..96 -> ind[63..95]
    __syncthreads();
    // BCE over upper triangle of permuted adjacency
    float bsum = 0.f;
    for (int idx = l; idx < NN; idx += 64) {
        int ii = idx / N, jj = idx - (idx / N) * N;
        if (jj >= ii) {
            float a = adj[indl[ii] * N + indl[jj]];
            float t = outv[triu_idx(ii, jj)];
            bsum += fmaxf(a, 0.f) - a * t + log1pf(expf(-fabsf(a)));
        }
    }
    for (int off = 32; off; off >>= 1) bsum += __shfl_down(bsum, off);
    if (l == 0) {
        float bce = bsum / (float)OUT_DIM;
        dout[0] = bce + klp[0];
    }
}

extern "C" void kernel_launch(void* const* d_in, const int* in_sizes, int n_in,
                              void* d_out, int out_size, void* d_ws, size_t ws_size,
                              hipStream_t stream) {
    const float* h   = (const float*)d_in[0];
    const float* adj = (const float*)d_in[1];
    const float* Wmu = (const float*)d_in[2];
    const float* bmu = (const float*)d_in[3];
    const float* Wls = (const float*)d_in[4];
    const float* bls = (const float*)d_in[5];
    const float* Wd1 = (const float*)d_in[6];
    const float* bd1 = (const float*)d_in[7];
    const float* Wd2 = (const float*)d_in[8];
    const float* bd2 = (const float*)d_in[9];

    float* ws   = (float*)d_ws;
    float* pmu  = ws + OFF_PMU;
    float* pls  = ws + OFF_PLS;
    float* mu   = ws + OFF_MU;
    float* ls   = ws + OFF_LS;
    float* pd1  = ws + OFF_PD1;
    float* y    = ws + OFF_Y;
    float* klp  = ws + OFF_KL;
    float* pd2  = ws + OFF_PD2;
    float* outv = ws + OFF_OUT;
    float* rec  = ws + OFF_REC;
    float* Bm   = ws + OFF_B;
    float* Dm   = ws + OFF_D;
    int*   ccnt = (int*)(ws + OFF_CCNT);
    int*   ccol = (int*)(ws + OFF_CCOL);
    float* cval = ws + OFF_CVAL;
    float* xA   = ws + OFF_XA;
    float* xB   = ws + OFF_XB;
    float* nrm  = ws + OFF_NRM;

    k_muls_partial<<<128, 256, 0, stream>>>(h, Wmu, Wls, pmu, pls);
    k_muls_reduce<<<4, 128, 0, stream>>>(pmu, pls, bmu, bls, mu, ls);
    k_d1_partial<<<128, 256, 0, stream>>>(h, mu, Wd1, pd1);
    k_d1_reduce_kl<<<1, 256, 0, stream>>>(pd1, bd1, mu, ls, y, klp);
    dim3 g5(19, 8);
    k_d2_partial<<<g5, 256, 0, stream>>>(y, Wd2, pd2);
    k_out_final<<<19, 256, 0, stream>>>(pd2, bd2, outv);
    k_build<<<1, 256, 0, stream>>>(adj, outv, rec, Bm, Dm, ccnt, ccol, cval, xA, nrm);
    for (int t = 0; t < MPM_ITERS; ++t) {
        const float* xi = (t & 1) ? xB : xA;
        float* xo = (t & 1) ? xA : xB;
        k_mpm_iter<<<MPM_BLOCKS, 384, 0, stream>>>(
            xi, xo, Bm, Dm, ccnt, ccol, cval,
            nrm + t * NRM_SLOTS, nrm + (t + 1) * NRM_SLOTS);
    }
    k_hungarian_bce<<<1, 64, 0, stream>>>(
        xA, nrm + MPM_ITERS * NRM_SLOTS, adj, outv, klp, (float*)d_out);
}

// Round 5
// 2574.024 us; speedup vs baseline: 1.8294x; 1.1237x over previous
//
#include <hip/hip_runtime.h>
#include <math.h>

#define N 96
#define NN 9216        // N*N
#define LATENT 256
#define OUT_DIM 4656   // N*(N+1)/2
#define MPM_ITERS 50
#define MPM_BLOCKS 24
#define NRM_SLOTS 24

// workspace offsets (in floats)
#define OFF_PMU    0        // 128*256
#define OFF_PLS    32768    // 128*256
#define OFF_PD1    65536    // 128*256 (h-part partials of d1)
#define OFF_Y      98816    // 256
#define OFF_KL     99072    // pad 64
#define OFF_PD2    99136    // 8*4656
#define OFF_OUT    136384   // 4656 (pad to 4672)
#define OFF_REC    141056   // 9216
#define OFF_B      150272   // 9216
#define OFF_D      159488   // 9216
#define OFF_CCNT   168704   // 96 ints
#define OFF_CCOL   168800   // 9216 ints
#define OFF_CVAL   178016   // 9216
#define OFF_XA     187232   // 9216
#define OFF_XB     196448   // 9216
#define OFF_NRM    205664   // 51*24
#define OFF_BAR    206896   // 2 uints (pad 16)

__device__ __forceinline__ int triu_idx(int i, int j) { // requires i<=j
    return i * N - (i * (i - 1)) / 2 + (j - i);
}

// monotone map f32 -> sortable u32 (preserves total order of non-NaN floats)
__device__ __forceinline__ unsigned fkey(float f) {
    unsigned b = __float_as_uint(f);
    return (b >> 31) ? ~b : (b | 0x80000000u);
}
__device__ __forceinline__ float funkey(unsigned k) {
    unsigned b = (k >> 31) ? (k & 0x7fffffffu) : ~k;
    return __uint_as_float(b);
}

// wave64 min-reduce of u32 via DPP (VALU-only, no DS ops); result uniform.
__device__ __forceinline__ unsigned wave_min_u32(unsigned x) {
    const int id = (int)0xFFFFFFFF;   // identity for min
    unsigned t;
    t = (unsigned)__builtin_amdgcn_update_dpp(id, (int)x, 0x111, 0xF, 0xF, false); if (t < x) x = t;
    t = (unsigned)__builtin_amdgcn_update_dpp(id, (int)x, 0x112, 0xF, 0xF, false); if (t < x) x = t;
    t = (unsigned)__builtin_amdgcn_update_dpp(id, (int)x, 0x114, 0xF, 0xF, false); if (t < x) x = t;
    t = (unsigned)__builtin_amdgcn_update_dpp(id, (int)x, 0x118, 0xF, 0xF, false); if (t < x) x = t;
    t = (unsigned)__builtin_amdgcn_update_dpp(id, (int)x, 0x142, 0xF, 0xF, false); if (t < x) x = t;
    t = (unsigned)__builtin_amdgcn_update_dpp(id, (int)x, 0x143, 0xF, 0xF, false); if (t < x) x = t;
    return (unsigned)__builtin_amdgcn_readlane((int)x, 63);
}

// device-scope sense-reversing grid barrier (all blocks co-resident)
__device__ __forceinline__ void grid_barrier(unsigned* cnt, unsigned* gen) {
    __syncthreads();
    if (threadIdx.x == 0) {
        __threadfence();   // release prior writes device-wide
        unsigned g = __hip_atomic_load(gen, __ATOMIC_RELAXED, __HIP_MEMORY_SCOPE_AGENT);
        unsigned a = __hip_atomic_fetch_add(cnt, 1u, __ATOMIC_ACQ_REL, __HIP_MEMORY_SCOPE_AGENT);
        if (a == MPM_BLOCKS - 1u) {
            __hip_atomic_store(cnt, 0u, __ATOMIC_RELAXED, __HIP_MEMORY_SCOPE_AGENT);
            __hip_atomic_store(gen, g + 1u, __ATOMIC_RELEASE, __HIP_MEMORY_SCOPE_AGENT);
        } else {
            while (__hip_atomic_load(gen, __ATOMIC_ACQUIRE, __HIP_MEMORY_SCOPE_AGENT) == g) {
                __builtin_amdgcn_s_sleep(8);
            }
        }
        __threadfence();   // acquire side
    }
    __syncthreads();
}

// ---- MLP stage 1 fused: partials of h@Wmu, h@Wls, h@Wd1[:NN] ----------------
__global__ __launch_bounds__(256) void k_mlp1(
        const float* __restrict__ h, const float* __restrict__ Wmu,
        const float* __restrict__ Wls, const float* __restrict__ Wd1,
        float* __restrict__ pmu, float* __restrict__ pls,
        float* __restrict__ pd1) {
    int j = threadIdx.x;
    int b = blockIdx.x;
    if (b < 128) {                       // mu & logstd partials, 72 rows each
        int k0 = b * 72;
        float amu = 0.f, als = 0.f;
        #pragma unroll 4
        for (int k = k0; k < k0 + 72; ++k) {
            float hv = h[k];
            amu = fmaf(hv, Wmu[k * LATENT + j], amu);
            als = fmaf(hv, Wls[k * LATENT + j], als);
        }
        pmu[b * LATENT + j] = amu;
        pls[b * LATENT + j] = als;
    } else {                             // d1 h-part partials, 72 rows each
        int c = b - 128;
        int k0 = c * 72;
        float acc = 0.f;
        #pragma unroll 4
        for (int k = k0; k < k0 + 72; ++k)
            acc = fmaf(h[k], Wd1[k * LATENT + j], acc);
        pd1[c * LATENT + j] = acc;
    }
}

// ---- MLP finish: mu/ls reduce, z@Wd1-tail, ReLU, KL -------------------------
__global__ __launch_bounds__(256) void k_mlp_finish(
        const float* __restrict__ pmu, const float* __restrict__ pls,
        const float* __restrict__ pd1, const float* __restrict__ bmu,
        const float* __restrict__ bls, const float* __restrict__ bd1,
        const float* __restrict__ Wd1, float* __restrict__ y,
        float* __restrict__ klp) {
    int j = threadIdx.x;
    __shared__ float mus[LATENT];
    __shared__ float red[4];
    float smu = 0.f, sls = 0.f, s1 = 0.f;
    for (int c = 0; c < 128; ++c) {
        smu += pmu[c * LATENT + j];
        sls += pls[c * LATENT + j];
        s1  += pd1[c * LATENT + j];
    }
    float mu_j = smu + bmu[j];
    float ls_j = sls + bls[j];
    mus[j] = mu_j;
    __syncthreads();
    float zp = 0.f;
    #pragma unroll 4
    for (int k = 0; k < LATENT; ++k)
        zp = fmaf(mus[k], Wd1[(NN + k) * LATENT + j], zp);
    y[j] = fmaxf(s1 + zp + bd1[j], 0.f);
    float v = 1.f + ls_j - mu_j * mu_j - expf(ls_j);
    for (int off = 32; off; off >>= 1) v += __shfl_down(v, off);
    if ((j & 63) == 0) red[j >> 6] = v;
    __syncthreads();
    if (j == 0) {
        float t = red[0] + red[1] + red[2] + red[3];
        klp[0] = -0.5f * t / (float)NN;
    }
}

// ---- MLP stage 3: decoder layer 2 + sigmoid --------------------------------
__global__ __launch_bounds__(256) void k_d2_partial(
        const float* __restrict__ y, const float* __restrict__ Wd2,
        float* __restrict__ pd2) {
    int o = blockIdx.x * 256 + threadIdx.x;
    int g = blockIdx.y;   // 0..7, 32 k's each
    if (o >= OUT_DIM) return;
    float s = 0.f;
    int k0 = g * 32;
    #pragma unroll 8
    for (int k = k0; k < k0 + 32; ++k) s = fmaf(y[k], Wd2[k * OUT_DIM + o], s);
    pd2[g * OUT_DIM + o] = s;
}

__global__ __launch_bounds__(256) void k_out_final(
        const float* __restrict__ pd2, const float* __restrict__ bd2,
        float* __restrict__ outv) {
    int o = blockIdx.x * 256 + threadIdx.x;
    if (o >= OUT_DIM) return;
    float s = bd2[o];
    for (int g = 0; g < 8; ++g) s += pd2[g * OUT_DIM + o];
    outv[o] = 1.f / (1.f + expf(-s));
}

// ---- graph construction: rec, B, D, CSR(A), x0, nrm init, barrier init -----
__global__ __launch_bounds__(256) void k_build(
        const float* __restrict__ adj, const float* __restrict__ outv,
        float* __restrict__ rec, float* __restrict__ Bm, float* __restrict__ Dm,
        int* __restrict__ ccnt, int* __restrict__ ccol, float* __restrict__ cval,
        float* __restrict__ xA, float* __restrict__ nrm, unsigned* __restrict__ bar) {
    int tid = threadIdx.x;
    __shared__ float d[N], nf[N], dr[N], nfr[N];
    for (int idx = tid; idx < NN; idx += 256) {
        int i = idx / N, j = idx - (idx / N) * N;
        int lo = (i < j) ? i : j, hi = (i < j) ? j : i;
        rec[idx] = outv[triu_idx(lo, hi)];
    }
    __syncthreads();
    if (tid < N) {
        int i = tid;
        d[i] = adj[i * N + i];
        dr[i] = rec[i * N + i];
        float s1 = 0.f, s2 = 0.f;
        for (int j = 0; j < N; ++j) { s1 += adj[i * N + j]; s2 += rec[i * N + j]; }
        nf[i] = s1; nfr[i] = s2;
    }
    __syncthreads();
    for (int idx = tid; idx < NN; idx += 256) {
        int i = idx / N, j = idx - (idx / N) * N;
        Bm[idx] = (i == j) ? 0.f : rec[idx] * dr[i] * dr[j];
        Dm[idx] = d[i] * dr[j] / (fabsf(nf[i] - nfr[j]) + 1.f);
        xA[idx] = 1.f / (float)N;
    }
    if (tid < N) {
        int i = tid, cnt = 0;
        for (int j = 0; j < N; ++j) {
            float av = adj[i * N + j] * d[i] * d[j];
            if (j != i && av != 0.f) { ccol[i * N + cnt] = j; cval[i * N + cnt] = av; ++cnt; }
        }
        ccnt[i] = cnt;
    }
    for (int idx = tid; idx < (MPM_ITERS + 1) * NRM_SLOTS; idx += 256) nrm[idx] = 0.f;
    if (tid == 0) nrm[0] = 1.f;   // ||x0||^2 = 9216 * (1/96)^2 = 1
    if (tid < 2) bar[tid] = 0u;   // grid-barrier cnt/gen
}

// ---- all 50 MPM iterations in one persistent kernel ------------------------
__global__ __launch_bounds__(384) void k_mpm_all(
        float* __restrict__ xA, float* __restrict__ xB,
        const float* __restrict__ Bm, const float* __restrict__ Dm,
        const int* __restrict__ ccnt, const int* __restrict__ ccol,
        const float* __restrict__ cval, float* __restrict__ nrm,
        unsigned* __restrict__ bar) {
    __shared__ float xs[N * 97];   // padded
    __shared__ float Bs[N * 4];    // Bs[b*4+al] = B[a0+al][b]
    __shared__ float Ms[N * 4];
    __shared__ float red[8];
    int tid = threadIdx.x;
    int al = tid & 3, j = tid >> 2;
    int a0 = blockIdx.x * 4;
    int i = j, a = a0 + al;
    // loop-invariant state
    Bs[tid] = Bm[(a0 + al) * N + (tid >> 2)];
    float dval = Dm[i * N + a];
    int cn = ccnt[i];
    __syncthreads();
    for (int t = 0; t < MPM_ITERS; ++t) {
        const float* xin = (t & 1) ? xB : xA;
        float* xout = (t & 1) ? xA : xB;
        float nsum = 0.f;
        const float* nr = nrm + t * NRM_SLOTS;
        for (int c = 0; c < NRM_SLOTS; ++c) nsum += nr[c];
        float rn = rsqrtf(nsum);
        for (int k = tid * 4; k < NN; k += 384 * 4) {   // N%4==0: no row-cross
            float4 vv = *(const float4*)(xin + k);
            int r = k / N, cc = k - r * N;
            float* xp = &xs[r * 97 + cc];
            xp[0] = vv.x; xp[1] = vv.y; xp[2] = vv.z; xp[3] = vv.w;
        }
        __syncthreads();
        float m = 0.f;
        const float* xr = &xs[j * 97];
        #pragma unroll 4
        for (int b = 0; b < N; ++b) m = fmaxf(m, xr[b] * Bs[b * 4 + al]);
        Ms[tid] = m;
        __syncthreads();
        float acc = xs[i * 97 + a] * dval;
        for (int c = 0; c < cn; ++c)
            acc = fmaf(cval[i * N + c], Ms[ccol[i * N + c] * 4 + al], acc);
        float o = acc * rn;
        xout[i * N + a] = o;
        float ps = o * o;
        for (int off = 32; off; off >>= 1) ps += __shfl_down(ps, off);
        if ((tid & 63) == 0) red[tid >> 6] = ps;
        __syncthreads();
        if (tid == 0) {
            float s = 0.f;
            for (int w = 0; w < 6; ++w) s += red[w];
            nrm[(t + 1) * NRM_SLOTS + blockIdx.x] = s;
        }
        if (t < MPM_ITERS - 1) grid_barrier(bar, bar + 1);
    }
}

// ---- Hungarian: single-wave, f32, DPP argmin, deferred u + BCE -------------
// Lane l owns columns: slot0 = col l (0..63), slot1 = col 64+l (l<33).
__global__ __launch_bounds__(64) void k_hungarian_bce(
        const float* __restrict__ xfin, const float* __restrict__ nrm50,
        const float* __restrict__ adj, const float* __restrict__ outv,
        const float* __restrict__ klp, float* __restrict__ dout) {
    __shared__ float costs[NN];
    __shared__ float u_sh[N + 1];
    __shared__ int indl[N];
    const float INF = 1e18f;
    int l = threadIdx.x;   // 0..63
    bool has1 = (l < 33);

    float nsum = 0.f;
    for (int c = 0; c < NRM_SLOTS; ++c) nsum += nrm50[c];
    float sc = rsqrtf(nsum);
    for (int k = l; k < NN; k += 64) costs[k] = -(xfin[k] * sc);
    u_sh[l] = 0.f;
    if (has1) u_sh[64 + l] = 0.f;
    if (l == 0) u_sh[N] = 0.f;
    __syncthreads();

    float v0 = 0.f, v1 = 0.f, minv0 = INF, minv1 = INF;
    int way0 = 0, way1 = 0, p0 = 0, p1 = 0;
    int used0 = 0, used1 = 0;
    const unsigned KINF = fkey(INF);

    for (int i = 1; i <= N; ++i) {
        minv0 = INF; minv1 = INF; used0 = 0; used1 = 0;
        float ud0 = 0.f, ud1 = 0.f;    // deferred u[p[col]] increments
        if (l == 0) p0 = i;            // p[0] = i
        int j0 = 0;
        int i0 = i;                    // = p[j0]
        while (true) {
            if (j0 < 64) { if (l == j0) used0 = 1; }
            else         { if (l == j0 - 64) used1 = 1; }
            float u_i0 = u_sh[i0];     // scan-start-stable (updates deferred)
            int rowbase = (i0 - 1) * N;
            if (l >= 1 && !used0) {
                float cur = costs[rowbase + (l - 1)] - u_i0 - v0;
                if (cur < minv0) { minv0 = cur; way0 = j0; }
            }
            if (has1 && !used1) {
                float cur = costs[rowbase + 63 + l] - u_i0 - v1;
                if (cur < minv1) { minv1 = cur; way1 = j0; }
            }
            unsigned ck0 = (l >= 1 && !used0) ? fkey(minv0 + 0.f) : KINF;
            unsigned ck1 = (has1 && !used1) ? fkey(minv1 + 0.f) : KINF;
            unsigned bv = (ck1 < ck0) ? ck1 : ck0;
            unsigned kmin = wave_min_u32(bv);
            unsigned long long m0 = __ballot(ck0 == kmin);
            unsigned long long m1 = __ballot(ck1 == kmin);
            int j1 = m0 ? (__ffsll(m0) - 1) : (64 + __ffsll(m1) - 1);
            float delta = funkey(kmin);
            if (used0) { ud0 += delta; v0 -= delta; }
            else if (l >= 1) minv0 -= delta;
            if (has1) {
                if (used1) { ud1 += delta; v1 -= delta; }
                else minv1 -= delta;
            }
            int pj1 = (j1 < 64) ? __builtin_amdgcn_readlane(p0, j1)
                                : __builtin_amdgcn_readlane(p1, j1 - 64);
            j0 = j1; i0 = pj1;
            if (pj1 == 0) break;
        }
        if (used0) u_sh[p0] += ud0;        // distinct rows -> race-free
        if (has1 && used1) u_sh[p1] += ud1;
        __syncthreads();
        while (j0) {                       // augment (uniform indices)
            int w = (j0 < 64) ? __builtin_amdgcn_readlane(way0, j0)
                              : __builtin_amdgcn_readlane(way1, j0 - 64);
            int pw = (w < 64) ? __builtin_amdgcn_readlane(p0, w)
                              : __builtin_amdgcn_readlane(p1, w - 64);
            if (j0 < 64) { if (l == j0) p0 = pw; }
            else         { if (l == j0 - 64) p1 = pw; }
            j0 = w;
        }
    }
    if (l >= 1) indl[l - 1] = p0 - 1;
    if (has1)   indl[63 + l] = p1 - 1;
    __syncthreads();
    float bsum = 0.f;
    for (int idx = l; idx < NN; idx += 64) {
        int ii = idx / N, jj = idx - (idx / N) * N;
        if (jj >= ii) {
            float aa = adj[indl[ii] * N + indl[jj]];
            float t = outv[triu_idx(ii, jj)];
            bsum += fmaxf(aa, 0.f) - aa * t + log1pf(expf(-fabsf(aa)));
        }
    }
    for (int off = 32; off; off >>= 1) bsum += __shfl_down(bsum, off);
    if (l == 0) {
        float bce = bsum / (float)OUT_DIM;
        dout[0] = bce + klp[0];
    }
}

extern "C" void kernel_launch(void* const* d_in, const int* in_sizes, int n_in,
                              void* d_out, int out_size, void* d_ws, size_t ws_size,
                              hipStream_t stream) {
    const float* h   = (const float*)d_in[0];
    const float* adj = (const float*)d_in[1];
    const float* Wmu = (const float*)d_in[2];
    const float* bmu = (const float*)d_in[3];
    const float* Wls = (const float*)d_in[4];
    const float* bls = (const float*)d_in[5];
    const float* Wd1 = (const float*)d_in[6];
    const float* bd1 = (const float*)d_in[7];
    const float* Wd2 = (const float*)d_in[8];
    const float* bd2 = (const float*)d_in[9];

    float* ws   = (float*)d_ws;
    float* pmu  = ws + OFF_PMU;
    float* pls  = ws + OFF_PLS;
    float* pd1  = ws + OFF_PD1;
    float* y    = ws + OFF_Y;
    float* klp  = ws + OFF_KL;
    float* pd2  = ws + OFF_PD2;
    float* outv = ws + OFF_OUT;
    float* rec  = ws + OFF_REC;
    float* Bm   = ws + OFF_B;
    float* Dm   = ws + OFF_D;
    int*   ccnt = (int*)(ws + OFF_CCNT);
    int*   ccol = (int*)(ws + OFF_CCOL);
    float* cval = ws + OFF_CVAL;
    float* xA   = ws + OFF_XA;
    float* xB   = ws + OFF_XB;
    float* nrm  = ws + OFF_NRM;
    unsigned* bar = (unsigned*)(ws + OFF_BAR);

    k_mlp1<<<256, 256, 0, stream>>>(h, Wmu, Wls, Wd1, pmu, pls, pd1);
    k_mlp_finish<<<1, 256, 0, stream>>>(pmu, pls, pd1, bmu, bls, bd1, Wd1, y, klp);
    dim3 g5(19, 8);
    k_d2_partial<<<g5, 256, 0, stream>>>(y, Wd2, pd2);
    k_out_final<<<19, 256, 0, stream>>>(pd2, bd2, outv);
    k_build<<<1, 256, 0, stream>>>(adj, outv, rec, Bm, Dm, ccnt, ccol, cval, xA, nrm, bar);
    k_mpm_all<<<MPM_BLOCKS, 384, 0, stream>>>(xA, xB, Bm, Dm, ccnt, ccol, cval, nrm, bar);
    // after 50 iters (even), final x is in xA
    k_hungarian_bce<<<1, 64, 0, stream>>>(
        xA, nrm + MPM_ITERS * NRM_SLOTS, adj, outv, klp, (float*)d_out);
}